// Round 1
// baseline (2033.965 us; speedup 1.0000x reference)
//
#include <hip/hip_runtime.h>
#include <cstddef>

#define D_MODEL   512
#define D_INNER   1024
#define D_STATE   16
#define DT_RANK   32
#define SEQ_L     1024
#define BATCH     2
#define NLAYER    2
#define M_ROWS    (BATCH * SEQ_L)   // 2048

__device__ __forceinline__ float softplus_f(float x) {
    return fmaxf(x, 0.f) + log1pf(expf(-fabsf(x)));
}
__device__ __forceinline__ float silu_f(float x) {
    return x / (1.f + __expf(-x));
}

// -------- embedding gather: x[m, :] = emb[ids[m], :] (float4 per thread) ----
__global__ void embed_kernel(const int* __restrict__ ids,
                             const float* __restrict__ emb,
                             float* __restrict__ x) {
    int g = blockIdx.x * blockDim.x + threadIdx.x;   // B*L*512/4 = 262144
    int c = (g & 127) << 2;                          // 128 float4 per row
    int m = g >> 7;
    int row = ids[m];
    *(float4*)&x[(size_t)m * D_MODEL + c] =
        *(const float4*)&emb[(size_t)row * D_MODEL + c];
}

// -------- rmsnorm per row of 512, one wave per row --------------------------
__global__ __launch_bounds__(64) void rmsnorm_kernel(const float* __restrict__ x,
                                                     const float* __restrict__ w,
                                                     float* __restrict__ out) {
    int row = blockIdx.x;
    int tid = threadIdx.x;
    const float* xp = x + (size_t)row * D_MODEL;
    float4 v0 = *(const float4*)&xp[tid * 4];
    float4 v1 = *(const float4*)&xp[256 + tid * 4];
    float ss = v0.x*v0.x + v0.y*v0.y + v0.z*v0.z + v0.w*v0.w
             + v1.x*v1.x + v1.y*v1.y + v1.z*v1.z + v1.w*v1.w;
    #pragma unroll
    for (int off = 32; off > 0; off >>= 1) ss += __shfl_xor(ss, off);
    float scale = rsqrtf(ss * (1.f / D_MODEL) + 1e-5f);
    float4 w0 = *(const float4*)&w[tid * 4];
    float4 w1 = *(const float4*)&w[256 + tid * 4];
    float* op = out + (size_t)row * D_MODEL;
    float4 o0, o1;
    o0.x = v0.x * scale * w0.x; o0.y = v0.y * scale * w0.y;
    o0.z = v0.z * scale * w0.z; o0.w = v0.w * scale * w0.w;
    o1.x = v1.x * scale * w1.x; o1.y = v1.y * scale * w1.y;
    o1.z = v1.z * scale * w1.z; o1.w = v1.w * scale * w1.w;
    *(float4*)&op[tid * 4] = o0;
    *(float4*)&op[256 + tid * 4] = o1;
}

// -------- generic tiled f32 GEMM: C = A[M,K] @ B[K,N]  ----------------------
// EPI: 0 = plain store; 1 = softplus(acc + bias[n]); 2 = C += acc (residual)
#define BM 64
#define BN 64
#define BKK 16
template<int EPI>
__global__ __launch_bounds__(256) void gemm_f32(const float* __restrict__ A,
                                                const float* __restrict__ Bm,
                                                const float* __restrict__ bias,
                                                float* __restrict__ C,
                                                int M, int N, int K,
                                                int lda, int ldb, int ldc) {
    __shared__ float As[BM][BKK + 4];
    __shared__ float Bs[BKK][BN];
    int tid = threadIdx.x;
    int n0 = blockIdx.x * BN;
    int m0 = blockIdx.y * BM;
    int tx4 = (tid & 15) << 2;
    int ty4 = (tid >> 4) << 2;
    int arow = tid >> 2, akk = (tid & 3) << 2;
    int brow = tid >> 4, bcol = (tid & 15) << 2;
    float acc[4][4] = {};
    for (int k0 = 0; k0 < K; k0 += BKK) {
        float4 av = *(const float4*)&A[(size_t)(m0 + arow) * lda + k0 + akk];
        float4 bv = *(const float4*)&Bm[(size_t)(k0 + brow) * ldb + n0 + bcol];
        *(float4*)&As[arow][akk] = av;
        *(float4*)&Bs[brow][bcol] = bv;
        __syncthreads();
        #pragma unroll
        for (int k = 0; k < BKK; ++k) {
            float a0 = As[ty4 + 0][k];
            float a1 = As[ty4 + 1][k];
            float a2 = As[ty4 + 2][k];
            float a3 = As[ty4 + 3][k];
            float4 b = *(float4*)&Bs[k][tx4];
            acc[0][0] = fmaf(a0, b.x, acc[0][0]); acc[0][1] = fmaf(a0, b.y, acc[0][1]);
            acc[0][2] = fmaf(a0, b.z, acc[0][2]); acc[0][3] = fmaf(a0, b.w, acc[0][3]);
            acc[1][0] = fmaf(a1, b.x, acc[1][0]); acc[1][1] = fmaf(a1, b.y, acc[1][1]);
            acc[1][2] = fmaf(a1, b.z, acc[1][2]); acc[1][3] = fmaf(a1, b.w, acc[1][3]);
            acc[2][0] = fmaf(a2, b.x, acc[2][0]); acc[2][1] = fmaf(a2, b.y, acc[2][1]);
            acc[2][2] = fmaf(a2, b.z, acc[2][2]); acc[2][3] = fmaf(a2, b.w, acc[2][3]);
            acc[3][0] = fmaf(a3, b.x, acc[3][0]); acc[3][1] = fmaf(a3, b.y, acc[3][1]);
            acc[3][2] = fmaf(a3, b.z, acc[3][2]); acc[3][3] = fmaf(a3, b.w, acc[3][3]);
        }
        __syncthreads();
    }
    #pragma unroll
    for (int i = 0; i < 4; ++i) {
        int m = m0 + ty4 + i;
        float* cp = &C[(size_t)m * ldc + n0 + tx4];
        float4 v = make_float4(acc[i][0], acc[i][1], acc[i][2], acc[i][3]);
        if (EPI == 1) {
            float4 bb = *(const float4*)&bias[n0 + tx4];
            v.x = softplus_f(v.x + bb.x); v.y = softplus_f(v.y + bb.y);
            v.z = softplus_f(v.z + bb.z); v.w = softplus_f(v.w + bb.w);
        } else if (EPI == 2) {
            float4 old = *(const float4*)cp;
            v.x += old.x; v.y += old.y; v.z += old.z; v.w += old.w;
        }
        *(float4*)cp = v;
    }
}

// -------- causal depthwise conv(4) + bias + SiLU ----------------------------
// reads xi = xr[:, 0:1024] (row stride 2048), writes xconv [M,1024]
__global__ void conv_silu_kernel(const float* __restrict__ xr,
                                 const float* __restrict__ cw,
                                 const float* __restrict__ cb,
                                 float* __restrict__ out) {
    int g = blockIdx.x * blockDim.x + threadIdx.x;  // M*1024
    int d = g & (D_INNER - 1);
    int m = g >> 10;
    int l = m & (SEQ_L - 1);
    float4 w = *(const float4*)&cw[d * 4];
    const float* col = &xr[(size_t)m * 2048 + d];
    float x3 = col[0];
    float x2 = (l >= 1) ? col[-2048] : 0.f;
    float x1 = (l >= 2) ? col[-4096] : 0.f;
    float x0 = (l >= 3) ? col[-6144] : 0.f;
    float acc = cb[d] + w.x * x0 + w.y * x1 + w.z * x2 + w.w * x3;
    out[g] = silu_f(acc);
}

// -------- selective scan + D skip + SiLU gate -------------------------------
// thread = (b, d); 16 states in registers; B_/C staged in LDS (8 timesteps)
__global__ __launch_bounds__(256) void scan_kernel(const float* __restrict__ u_,
                                                   const float* __restrict__ delta,
                                                   const float* __restrict__ xdbl,
                                                   const float* __restrict__ A_log,
                                                   const float* __restrict__ Dp,
                                                   const float* __restrict__ xr,
                                                   float* __restrict__ y) {
    int d = blockIdx.x * 256 + threadIdx.x;
    int b = blockIdx.y;
    int tid = threadIdx.x;
    float A_[D_STATE], h[D_STATE];
    #pragma unroll
    for (int n = 0; n < D_STATE; ++n) {
        A_[n] = -__expf(A_log[(size_t)d * D_STATE + n]);
        h[n] = 0.f;
    }
    float Dd = Dp[d];
    __shared__ float sBC[8][32];
    int r_ = tid >> 5, c_ = tid & 31;
    for (int l0 = 0; l0 < SEQ_L; l0 += 8) {
        __syncthreads();
        sBC[r_][c_] = xdbl[((size_t)(b * SEQ_L + l0 + r_)) * 64 + 32 + c_];
        __syncthreads();
        #pragma unroll 1
        for (int r = 0; r < 8; ++r) {
            int m = b * SEQ_L + l0 + r;
            float dt = delta[(size_t)m * D_INNER + d];
            float uu = u_[(size_t)m * D_INNER + d];
            float yv = 0.f;
            #pragma unroll
            for (int n = 0; n < D_STATE; ++n) {
                float dA = __expf(dt * A_[n]);
                h[n] = dA * h[n] + (dt * sBC[r][n]) * uu;
                yv = fmaf(h[n], sBC[r][16 + n], yv);
            }
            yv = fmaf(uu, Dd, yv);
            float res = xr[(size_t)m * 2048 + 1024 + d];
            y[(size_t)m * D_INNER + d] = yv * silu_f(res);
        }
    }
}

// -------- mean over L after final rmsnorm -----------------------------------
__global__ __launch_bounds__(512) void pool_kernel(const float* __restrict__ xf,
                                                   float* __restrict__ pooled) {
    int b = blockIdx.x;
    int d = threadIdx.x;
    float s = 0.f;
    for (int l = 0; l < SEQ_L; ++l)
        s += xf[((size_t)b * SEQ_L + l) * D_MODEL + d];
    pooled[b * D_MODEL + d] = s * (1.f / SEQ_L);
}

// -------- pooled @ proj_w + proj_b -> emotion_emb ---------------------------
__global__ void emb_proj_kernel(const float* __restrict__ pooled,
                                const float* __restrict__ pw,
                                const float* __restrict__ pb,
                                float* __restrict__ out) {
    int b = blockIdx.x;
    int e = threadIdx.x;   // 256
    float acc = pb[e];
    for (int k = 0; k < D_MODEL; ++k)
        acc = fmaf(pooled[b * D_MODEL + k], pw[k * 256 + e], acc);
    out[b * 256 + e] = acc;
}

// -------- emotion_emb @ cls_w + cls_b -> logits -----------------------------
__global__ void logits_kernel(const float* __restrict__ embv,
                              const float* __restrict__ cw,
                              const float* __restrict__ cb,
                              float* __restrict__ out) {
    int t = threadIdx.x;
    if (t < 14) {
        int b = t / 7, c = t % 7;
        float acc = cb[c];
        for (int k = 0; k < 256; ++k)
            acc = fmaf(embv[b * 256 + k], cw[k * 7 + c], acc);
        out[b * 7 + c] = acc;
    }
}

extern "C" void kernel_launch(void* const* d_in, const int* in_sizes, int n_in,
                              void* d_out, int out_size, void* d_ws, size_t ws_size,
                              hipStream_t stream) {
    const int*   ids    = (const int*)d_in[0];
    const float* emb    = (const float*)d_in[1];
    const float* norm_w = (const float*)d_in[2];
    const float* in_w   = (const float*)d_in[3];
    const float* conv_w = (const float*)d_in[4];
    const float* conv_b = (const float*)d_in[5];
    const float* xp_w   = (const float*)d_in[6];
    const float* dt_w   = (const float*)d_in[7];
    const float* dt_b   = (const float*)d_in[8];
    const float* A_log  = (const float*)d_in[9];
    const float* Dp     = (const float*)d_in[10];
    const float* out_w  = (const float*)d_in[11];
    const float* normf  = (const float*)d_in[12];
    const float* proj_w = (const float*)d_in[13];
    const float* proj_b = (const float*)d_in[14];
    const float* cls_w  = (const float*)d_in[15];
    const float* cls_b  = (const float*)d_in[16];
    float* out = (float*)d_out;

    float* ws     = (float*)d_ws;
    float* x      = ws;                      // 1,048,576
    float* xn     = x + 1048576;             // 1,048,576
    float* xr     = xn + 1048576;            // 4,194,304
    float* xconv  = xr + 4194304;            // 2,097,152
    float* xdbl   = xconv + 2097152;         //   131,072
    float* delta  = xdbl + 131072;           // 2,097,152
    float* yb     = delta + 2097152;         // 2,097,152
    float* pooled = yb + 2097152;            //     1,024

    embed_kernel<<<1024, 256, 0, stream>>>(ids, emb, x);

    for (int i = 0; i < NLAYER; ++i) {
        rmsnorm_kernel<<<M_ROWS, 64, 0, stream>>>(x, norm_w + i * D_MODEL, xn);
        gemm_f32<0><<<dim3(2048 / BN, M_ROWS / BM), 256, 0, stream>>>(
            xn, in_w + (size_t)i * D_MODEL * 2 * D_INNER, nullptr, xr,
            M_ROWS, 2048, 512, 512, 2048, 2048);
        conv_silu_kernel<<<(M_ROWS * D_INNER) / 256, 256, 0, stream>>>(
            xr, conv_w + i * D_INNER * 4, conv_b + i * D_INNER, xconv);
        gemm_f32<0><<<dim3(64 / BN, M_ROWS / BM), 256, 0, stream>>>(
            xconv, xp_w + (size_t)i * D_INNER * 64, nullptr, xdbl,
            M_ROWS, 64, 1024, 1024, 64, 64);
        gemm_f32<1><<<dim3(1024 / BN, M_ROWS / BM), 256, 0, stream>>>(
            xdbl, dt_w + (size_t)i * DT_RANK * D_INNER, dt_b + i * D_INNER, delta,
            M_ROWS, 1024, 32, 64, 1024, 1024);
        scan_kernel<<<dim3(D_INNER / 256, BATCH), 256, 0, stream>>>(
            xconv, delta, xdbl, A_log + i * D_INNER * D_STATE, Dp + i * D_INNER,
            xr, yb);
        gemm_f32<2><<<dim3(512 / BN, M_ROWS / BM), 256, 0, stream>>>(
            yb, out_w + (size_t)i * D_INNER * D_MODEL, nullptr, x,
            M_ROWS, 512, 1024, 1024, 512, 512);
    }

    rmsnorm_kernel<<<M_ROWS, 64, 0, stream>>>(x, normf, xn);
    pool_kernel<<<BATCH, 512, 0, stream>>>(xn, pooled);
    emb_proj_kernel<<<BATCH, 256, 0, stream>>>(pooled, proj_w, proj_b, out + 14);
    logits_kernel<<<1, 64, 0, stream>>>(out + 14, cls_w, cls_b, out);
}

// Round 2
// 568.883 us; speedup vs baseline: 3.5754x; 3.5754x over previous
//
#include <hip/hip_runtime.h>
#include <cstddef>

#define D_MODEL   512
#define D_INNER   1024
#define D_STATE   16
#define DT_RANK   32
#define SEQ_L     1024
#define BATCH     2
#define NLAYER    2
#define M_ROWS    (BATCH * SEQ_L)   // 2048
#define NC        32                // scan chunks
#define LC        (SEQ_L / NC)      // 32 timesteps per chunk

__device__ __forceinline__ float softplus_f(float x) {
    return fmaxf(x, 0.f) + log1pf(expf(-fabsf(x)));
}
__device__ __forceinline__ float silu_f(float x) {
    return x / (1.f + __expf(-x));
}

// -------- embedding gather: x[m, :] = emb[ids[m], :] (float4 per thread) ----
__global__ void embed_kernel(const int* __restrict__ ids,
                             const float* __restrict__ emb,
                             float* __restrict__ x) {
    int g = blockIdx.x * blockDim.x + threadIdx.x;   // B*L*512/4 = 262144
    int c = (g & 127) << 2;                          // 128 float4 per row
    int m = g >> 7;
    int row = ids[m];
    *(float4*)&x[(size_t)m * D_MODEL + c] =
        *(const float4*)&emb[(size_t)row * D_MODEL + c];
}

// -------- rmsnorm per row of 512, one wave per row --------------------------
__global__ __launch_bounds__(64) void rmsnorm_kernel(const float* __restrict__ x,
                                                     const float* __restrict__ w,
                                                     float* __restrict__ out) {
    int row = blockIdx.x;
    int tid = threadIdx.x;
    const float* xp = x + (size_t)row * D_MODEL;
    float4 v0 = *(const float4*)&xp[tid * 4];
    float4 v1 = *(const float4*)&xp[256 + tid * 4];
    float ss = v0.x*v0.x + v0.y*v0.y + v0.z*v0.z + v0.w*v0.w
             + v1.x*v1.x + v1.y*v1.y + v1.z*v1.z + v1.w*v1.w;
    #pragma unroll
    for (int off = 32; off > 0; off >>= 1) ss += __shfl_xor(ss, off);
    float scale = rsqrtf(ss * (1.f / D_MODEL) + 1e-5f);
    float4 w0 = *(const float4*)&w[tid * 4];
    float4 w1 = *(const float4*)&w[256 + tid * 4];
    float* op = out + (size_t)row * D_MODEL;
    float4 o0, o1;
    o0.x = v0.x * scale * w0.x; o0.y = v0.y * scale * w0.y;
    o0.z = v0.z * scale * w0.z; o0.w = v0.w * scale * w0.w;
    o1.x = v1.x * scale * w1.x; o1.y = v1.y * scale * w1.y;
    o1.z = v1.z * scale * w1.z; o1.w = v1.w * scale * w1.w;
    *(float4*)&op[tid * 4] = o0;
    *(float4*)&op[256 + tid * 4] = o1;
}

// -------- generic tiled f32 GEMM: C = A[M,K] @ B[K,N]  ----------------------
// EPI: 0 = plain store; 1 = softplus(acc + bias[n]); 2 = C += acc (residual)
#define BM 64
#define BN 64
#define BKK 16
template<int EPI>
__global__ __launch_bounds__(256) void gemm_f32(const float* __restrict__ A,
                                                const float* __restrict__ Bm,
                                                const float* __restrict__ bias,
                                                float* __restrict__ C,
                                                int M, int N, int K,
                                                int lda, int ldb, int ldc) {
    __shared__ float As[BM][BKK + 4];
    __shared__ float Bs[BKK][BN];
    int tid = threadIdx.x;
    int n0 = blockIdx.x * BN;
    int m0 = blockIdx.y * BM;
    int tx4 = (tid & 15) << 2;
    int ty4 = (tid >> 4) << 2;
    int arow = tid >> 2, akk = (tid & 3) << 2;
    int brow = tid >> 4, bcol = (tid & 15) << 2;
    float acc[4][4] = {};
    for (int k0 = 0; k0 < K; k0 += BKK) {
        float4 av = *(const float4*)&A[(size_t)(m0 + arow) * lda + k0 + akk];
        float4 bv = *(const float4*)&Bm[(size_t)(k0 + brow) * ldb + n0 + bcol];
        *(float4*)&As[arow][akk] = av;
        *(float4*)&Bs[brow][bcol] = bv;
        __syncthreads();
        #pragma unroll
        for (int k = 0; k < BKK; ++k) {
            float a0 = As[ty4 + 0][k];
            float a1 = As[ty4 + 1][k];
            float a2 = As[ty4 + 2][k];
            float a3 = As[ty4 + 3][k];
            float4 b = *(float4*)&Bs[k][tx4];
            acc[0][0] = fmaf(a0, b.x, acc[0][0]); acc[0][1] = fmaf(a0, b.y, acc[0][1]);
            acc[0][2] = fmaf(a0, b.z, acc[0][2]); acc[0][3] = fmaf(a0, b.w, acc[0][3]);
            acc[1][0] = fmaf(a1, b.x, acc[1][0]); acc[1][1] = fmaf(a1, b.y, acc[1][1]);
            acc[1][2] = fmaf(a1, b.z, acc[1][2]); acc[1][3] = fmaf(a1, b.w, acc[1][3]);
            acc[2][0] = fmaf(a2, b.x, acc[2][0]); acc[2][1] = fmaf(a2, b.y, acc[2][1]);
            acc[2][2] = fmaf(a2, b.z, acc[2][2]); acc[2][3] = fmaf(a2, b.w, acc[2][3]);
            acc[3][0] = fmaf(a3, b.x, acc[3][0]); acc[3][1] = fmaf(a3, b.y, acc[3][1]);
            acc[3][2] = fmaf(a3, b.z, acc[3][2]); acc[3][3] = fmaf(a3, b.w, acc[3][3]);
        }
        __syncthreads();
    }
    #pragma unroll
    for (int i = 0; i < 4; ++i) {
        int m = m0 + ty4 + i;
        float* cp = &C[(size_t)m * ldc + n0 + tx4];
        float4 v = make_float4(acc[i][0], acc[i][1], acc[i][2], acc[i][3]);
        if (EPI == 1) {
            float4 bb = *(const float4*)&bias[n0 + tx4];
            v.x = softplus_f(v.x + bb.x); v.y = softplus_f(v.y + bb.y);
            v.z = softplus_f(v.z + bb.z); v.w = softplus_f(v.w + bb.w);
        } else if (EPI == 2) {
            float4 old = *(const float4*)cp;
            v.x += old.x; v.y += old.y; v.z += old.z; v.w += old.w;
        }
        *(float4*)cp = v;
    }
}

// -------- causal depthwise conv(4) + bias + SiLU ----------------------------
__global__ void conv_silu_kernel(const float* __restrict__ xr,
                                 const float* __restrict__ cw,
                                 const float* __restrict__ cb,
                                 float* __restrict__ out) {
    int g = blockIdx.x * blockDim.x + threadIdx.x;  // M*1024
    int d = g & (D_INNER - 1);
    int m = g >> 10;
    int l = m & (SEQ_L - 1);
    float4 w = *(const float4*)&cw[d * 4];
    const float* col = &xr[(size_t)m * 2048 + d];
    float x3 = col[0];
    float x2 = (l >= 1) ? col[-2048] : 0.f;
    float x1 = (l >= 2) ? col[-4096] : 0.f;
    float x0 = (l >= 3) ? col[-6144] : 0.f;
    float acc = cb[d] + w.x * x0 + w.y * x1 + w.z * x2 + w.w * x3;
    out[g] = silu_f(acc);
}

// ======================= chunk-parallel selective scan =======================
// Recurrence per (b,d,n): h_l = exp(dt_l*A_n)*h_{l-1} + dt_l*B_ln*u_l
// P1: per-chunk transfer (aprod = prod of dA, hloc = local result from h=0)
// P2: sequential scan over NC chunk summaries; writes chunk-init IN PLACE
//     over hloc (read-before-write within the owning thread).
// P3: re-run chunk with true init; emit y = sum_n h*C + u*D, gated by silu(res).

__global__ __launch_bounds__(256) void scan_p1(const float* __restrict__ u_,
                                               const float* __restrict__ delta,
                                               const float* __restrict__ xdbl,
                                               const float* __restrict__ A_log,
                                               float* __restrict__ aprod,
                                               float* __restrict__ hloc) {
    int d = blockIdx.x * 256 + threadIdx.x;
    int b = blockIdx.y;
    int c = blockIdx.z;
    int l0 = c * LC;
    __shared__ float sB[LC][D_STATE];
    for (int i = threadIdx.x; i < LC * D_STATE; i += 256) {
        int l = i >> 4, n = i & 15;
        sB[l][n] = xdbl[((size_t)(b * SEQ_L + l0 + l)) * 64 + DT_RANK + n];
    }
    __syncthreads();
    float A_[D_STATE], h[D_STATE], ap[D_STATE];
    #pragma unroll
    for (int n = 0; n < D_STATE; ++n) {
        A_[n] = -__expf(A_log[(size_t)d * D_STATE + n]);
        h[n] = 0.f; ap[n] = 1.f;
    }
    for (int l = 0; l < LC; ++l) {
        size_t m = (size_t)b * SEQ_L + l0 + l;
        float dt = delta[m * D_INNER + d];
        float uu = u_[m * D_INNER + d];
        float du = dt * uu;
        #pragma unroll
        for (int n = 0; n < D_STATE; ++n) {
            float e = __expf(dt * A_[n]);
            h[n] = fmaf(e, h[n], du * sB[l][n]);
            ap[n] *= e;
        }
    }
    #pragma unroll
    for (int n = 0; n < D_STATE; ++n) {
        size_t o = (((size_t)b * NC + c) * D_STATE + n) * D_INNER + d;
        aprod[o] = ap[n];
        hloc[o] = h[n];
    }
}

__global__ __launch_bounds__(256) void scan_p2(const float* __restrict__ aprod,
                                               float* __restrict__ hloc) {
    // grid (D_INNER/256, D_STATE, BATCH); thread owns one (b,n,d) recurrence
    int d = blockIdx.x * 256 + threadIdx.x;
    int n = blockIdx.y;
    int b = blockIdx.z;
    float h = 0.f;
    for (int c = 0; c < NC; ++c) {
        size_t o = (((size_t)b * NC + c) * D_STATE + n) * D_INNER + d;
        float ap = aprod[o];
        float lc = hloc[o];
        hloc[o] = h;                 // becomes h_init for chunk c
        h = fmaf(ap, h, lc);
    }
}

__global__ __launch_bounds__(256) void scan_p3(const float* __restrict__ u_,
                                               const float* __restrict__ delta,
                                               const float* __restrict__ xdbl,
                                               const float* __restrict__ A_log,
                                               const float* __restrict__ Dp,
                                               const float* __restrict__ hinit,
                                               const float* __restrict__ xr,
                                               float* __restrict__ y) {
    int d = blockIdx.x * 256 + threadIdx.x;
    int b = blockIdx.y;
    int c = blockIdx.z;
    int l0 = c * LC;
    __shared__ float sBC[LC][2 * D_STATE];
    for (int i = threadIdx.x; i < LC * 2 * D_STATE; i += 256) {
        int l = i >> 5, j = i & 31;
        sBC[l][j] = xdbl[((size_t)(b * SEQ_L + l0 + l)) * 64 + DT_RANK + j];
    }
    __syncthreads();
    float A_[D_STATE], h[D_STATE];
    #pragma unroll
    for (int n = 0; n < D_STATE; ++n) {
        A_[n] = -__expf(A_log[(size_t)d * D_STATE + n]);
        size_t o = (((size_t)b * NC + c) * D_STATE + n) * D_INNER + d;
        h[n] = hinit[o];
    }
    float Dd = Dp[d];
    for (int l = 0; l < LC; ++l) {
        size_t m = (size_t)b * SEQ_L + l0 + l;
        float dt = delta[m * D_INNER + d];
        float uu = u_[m * D_INNER + d];
        float du = dt * uu;
        float yv = 0.f;
        #pragma unroll
        for (int n = 0; n < D_STATE; ++n) {
            float e = __expf(dt * A_[n]);
            h[n] = fmaf(e, h[n], du * sBC[l][n]);
            yv = fmaf(h[n], sBC[l][D_STATE + n], yv);
        }
        yv = fmaf(uu, Dd, yv);
        float res = xr[m * 2048 + 1024 + d];
        y[m * D_INNER + d] = yv * silu_f(res);
    }
}

// -------- mean over L after final rmsnorm -----------------------------------
__global__ __launch_bounds__(512) void pool_kernel(const float* __restrict__ xf,
                                                   float* __restrict__ pooled) {
    int b = blockIdx.x;
    int d = threadIdx.x;
    float s = 0.f;
    for (int l = 0; l < SEQ_L; ++l)
        s += xf[((size_t)b * SEQ_L + l) * D_MODEL + d];
    pooled[b * D_MODEL + d] = s * (1.f / SEQ_L);
}

__global__ void emb_proj_kernel(const float* __restrict__ pooled,
                                const float* __restrict__ pw,
                                const float* __restrict__ pb,
                                float* __restrict__ out) {
    int b = blockIdx.x;
    int e = threadIdx.x;   // 256
    float acc = pb[e];
    for (int k = 0; k < D_MODEL; ++k)
        acc = fmaf(pooled[b * D_MODEL + k], pw[k * 256 + e], acc);
    out[b * 256 + e] = acc;
}

__global__ void logits_kernel(const float* __restrict__ embv,
                              const float* __restrict__ cw,
                              const float* __restrict__ cb,
                              float* __restrict__ out) {
    int t = threadIdx.x;
    if (t < 14) {
        int b = t / 7, c = t % 7;
        float acc = cb[c];
        for (int k = 0; k < 256; ++k)
            acc = fmaf(embv[b * 256 + k], cw[k * 7 + c], acc);
        out[b * 7 + c] = acc;
    }
}

extern "C" void kernel_launch(void* const* d_in, const int* in_sizes, int n_in,
                              void* d_out, int out_size, void* d_ws, size_t ws_size,
                              hipStream_t stream) {
    const int*   ids    = (const int*)d_in[0];
    const float* emb    = (const float*)d_in[1];
    const float* norm_w = (const float*)d_in[2];
    const float* in_w   = (const float*)d_in[3];
    const float* conv_w = (const float*)d_in[4];
    const float* conv_b = (const float*)d_in[5];
    const float* xp_w   = (const float*)d_in[6];
    const float* dt_w   = (const float*)d_in[7];
    const float* dt_b   = (const float*)d_in[8];
    const float* A_log  = (const float*)d_in[9];
    const float* Dp     = (const float*)d_in[10];
    const float* out_w  = (const float*)d_in[11];
    const float* normf  = (const float*)d_in[12];
    const float* proj_w = (const float*)d_in[13];
    const float* proj_b = (const float*)d_in[14];
    const float* cls_w  = (const float*)d_in[15];
    const float* cls_b  = (const float*)d_in[16];
    float* out = (float*)d_out;

    float* ws     = (float*)d_ws;
    float* x      = ws;                      // 1,048,576 f
    float* xn     = x + 1048576;             // 1,048,576 f (also hloc/hinit)
    float* xr     = xn + 1048576;            // 4,194,304 f
    float* xconv  = xr + 4194304;            // 2,097,152 f
    float* xdbl   = xconv + 2097152;         //   131,072 f
    float* delta  = xdbl + 131072;           // 2,097,152 f
    float* yb     = delta + 2097152;         // 2,097,152 f (first 1M = aprod)
    float* pooled = yb + 2097152;            //     1,024 f
    float* aprod  = yb;                      // dead until scan_p3 writes yb
    float* hloc   = xn;                      // xn dead between in_proj and next rmsnorm

    embed_kernel<<<1024, 256, 0, stream>>>(ids, emb, x);

    for (int i = 0; i < NLAYER; ++i) {
        rmsnorm_kernel<<<M_ROWS, 64, 0, stream>>>(x, norm_w + i * D_MODEL, xn);
        gemm_f32<0><<<dim3(2048 / BN, M_ROWS / BM), 256, 0, stream>>>(
            xn, in_w + (size_t)i * D_MODEL * 2 * D_INNER, nullptr, xr,
            M_ROWS, 2048, 512, 512, 2048, 2048);
        conv_silu_kernel<<<(M_ROWS * D_INNER) / 256, 256, 0, stream>>>(
            xr, conv_w + i * D_INNER * 4, conv_b + i * D_INNER, xconv);
        gemm_f32<0><<<dim3(64 / BN, M_ROWS / BM), 256, 0, stream>>>(
            xconv, xp_w + (size_t)i * D_INNER * 64, nullptr, xdbl,
            M_ROWS, 64, 1024, 1024, 64, 64);
        gemm_f32<1><<<dim3(1024 / BN, M_ROWS / BM), 256, 0, stream>>>(
            xdbl, dt_w + (size_t)i * DT_RANK * D_INNER, dt_b + i * D_INNER, delta,
            M_ROWS, 1024, 32, 64, 1024, 1024);

        scan_p1<<<dim3(D_INNER / 256, BATCH, NC), 256, 0, stream>>>(
            xconv, delta, xdbl, A_log + (size_t)i * D_INNER * D_STATE, aprod, hloc);
        scan_p2<<<dim3(D_INNER / 256, D_STATE, BATCH), 256, 0, stream>>>(
            aprod, hloc);
        scan_p3<<<dim3(D_INNER / 256, BATCH, NC), 256, 0, stream>>>(
            xconv, delta, xdbl, A_log + (size_t)i * D_INNER * D_STATE,
            Dp + (size_t)i * D_INNER, hloc, xr, yb);

        gemm_f32<2><<<dim3(512 / BN, M_ROWS / BM), 256, 0, stream>>>(
            yb, out_w + (size_t)i * D_INNER * D_MODEL, nullptr, x,
            M_ROWS, 512, 1024, 1024, 512, 512);
    }

    rmsnorm_kernel<<<M_ROWS, 64, 0, stream>>>(x, normf, xn);
    pool_kernel<<<BATCH, 512, 0, stream>>>(xn, pooled);
    emb_proj_kernel<<<BATCH, 256, 0, stream>>>(pooled, proj_w, proj_b, out + 14);
    logits_kernel<<<1, 64, 0, stream>>>(out + 14, cls_w, cls_b, out);
}

// Round 3
// 322.704 us; speedup vs baseline: 6.3029x; 1.7629x over previous
//
#include <hip/hip_runtime.h>
#include <cstddef>

#define D_MODEL   512
#define D_INNER   1024
#define D_STATE   16
#define DT_RANK   32
#define SEQ_L     1024
#define BATCH     2
#define NLAYER    2
#define M_ROWS    (BATCH * SEQ_L)   // 2048
#define NC        32                // scan chunks
#define LC        (SEQ_L / NC)      // 32 timesteps per chunk

typedef __bf16 bf16x8 __attribute__((ext_vector_type(8)));
typedef float  f32x4  __attribute__((ext_vector_type(4)));

__device__ __forceinline__ float softplus_f(float x) {
    return fmaxf(x, 0.f) + log1pf(expf(-fabsf(x)));
}
__device__ __forceinline__ float silu_f(float x) {
    return x / (1.f + __expf(-x));
}
__device__ __forceinline__ unsigned short f2bf(float f) {
    unsigned u = __float_as_uint(f);
    return (unsigned short)((u + 0x7fffu + ((u >> 16) & 1u)) >> 16);
}
__device__ __forceinline__ unsigned pack_bf2(float lo, float hi) {
    return (unsigned)f2bf(lo) | ((unsigned)f2bf(hi) << 16);
}

// -------- embedding gather --------------------------------------------------
__global__ void embed_kernel(const int* __restrict__ ids,
                             const float* __restrict__ emb,
                             float* __restrict__ x) {
    int g = blockIdx.x * blockDim.x + threadIdx.x;
    int c = (g & 127) << 2;
    int m = g >> 7;
    int row = ids[m];
    *(float4*)&x[(size_t)m * D_MODEL + c] =
        *(const float4*)&emb[(size_t)row * D_MODEL + c];
}

// -------- rmsnorm (f32 out, for final) --------------------------------------
__global__ __launch_bounds__(64) void rmsnorm_kernel(const float* __restrict__ x,
                                                     const float* __restrict__ w,
                                                     float* __restrict__ out) {
    int row = blockIdx.x;
    int tid = threadIdx.x;
    const float* xp = x + (size_t)row * D_MODEL;
    float4 v0 = *(const float4*)&xp[tid * 4];
    float4 v1 = *(const float4*)&xp[256 + tid * 4];
    float ss = v0.x*v0.x + v0.y*v0.y + v0.z*v0.z + v0.w*v0.w
             + v1.x*v1.x + v1.y*v1.y + v1.z*v1.z + v1.w*v1.w;
    #pragma unroll
    for (int off = 32; off > 0; off >>= 1) ss += __shfl_xor(ss, off);
    float scale = rsqrtf(ss * (1.f / D_MODEL) + 1e-5f);
    float4 w0 = *(const float4*)&w[tid * 4];
    float4 w1 = *(const float4*)&w[256 + tid * 4];
    float* op = out + (size_t)row * D_MODEL;
    float4 o0, o1;
    o0.x = v0.x * scale * w0.x; o0.y = v0.y * scale * w0.y;
    o0.z = v0.z * scale * w0.z; o0.w = v0.w * scale * w0.w;
    o1.x = v1.x * scale * w1.x; o1.y = v1.y * scale * w1.y;
    o1.z = v1.z * scale * w1.z; o1.w = v1.w * scale * w1.w;
    *(float4*)&op[tid * 4] = o0;
    *(float4*)&op[256 + tid * 4] = o1;
}

// -------- rmsnorm (bf16 out, feeds MFMA in_proj) ----------------------------
__global__ __launch_bounds__(64) void rmsnorm_bf_kernel(const float* __restrict__ x,
                                                        const float* __restrict__ w,
                                                        unsigned short* __restrict__ out) {
    int row = blockIdx.x;
    int tid = threadIdx.x;
    const float* xp = x + (size_t)row * D_MODEL;
    float4 v0 = *(const float4*)&xp[tid * 4];
    float4 v1 = *(const float4*)&xp[256 + tid * 4];
    float ss = v0.x*v0.x + v0.y*v0.y + v0.z*v0.z + v0.w*v0.w
             + v1.x*v1.x + v1.y*v1.y + v1.z*v1.z + v1.w*v1.w;
    #pragma unroll
    for (int off = 32; off > 0; off >>= 1) ss += __shfl_xor(ss, off);
    float scale = rsqrtf(ss * (1.f / D_MODEL) + 1e-5f);
    float4 w0 = *(const float4*)&w[tid * 4];
    float4 w1 = *(const float4*)&w[256 + tid * 4];
    unsigned short* op = out + (size_t)row * D_MODEL;
    uint2 p0, p1;
    p0.x = pack_bf2(v0.x * scale * w0.x, v0.y * scale * w0.y);
    p0.y = pack_bf2(v0.z * scale * w0.z, v0.w * scale * w0.w);
    p1.x = pack_bf2(v1.x * scale * w1.x, v1.y * scale * w1.y);
    p1.y = pack_bf2(v1.z * scale * w1.z, v1.w * scale * w1.w);
    *(uint2*)&op[tid * 4] = p0;
    *(uint2*)&op[256 + tid * 4] = p1;
}

// -------- cast + transpose weight: W f32 [K][N] -> Wt bf16 [N][K] -----------
__global__ __launch_bounds__(256) void castT_kernel(const float* __restrict__ W,
                                                    unsigned short* __restrict__ Wt,
                                                    int K, int N) {
    __shared__ float tile[32][33];
    int n0 = blockIdx.x * 32, k0 = blockIdx.y * 32;
    int tx = threadIdx.x & 31, ty = threadIdx.x >> 5;   // ty 0..7
    #pragma unroll
    for (int i = 0; i < 4; ++i)
        tile[ty + i*8][tx] = W[(size_t)(k0 + ty + i*8) * N + n0 + tx];
    __syncthreads();
    #pragma unroll
    for (int i = 0; i < 4; ++i)
        Wt[(size_t)(n0 + ty + i*8) * K + k0 + tx] = f2bf(tile[tx][ty + i*8]);
}

// -------- bf16 MFMA GEMM: C[M,N](f32) = A[M,K](bf16) @ Bt[N,K](bf16)^T ------
// 64x64 tile, BK=64, 4 waves (2x2), XOR-swizzled LDS, global_load_lds staging.
// EPI: 0 = store, 2 = accumulate into C.
template<int EPI>
__global__ __launch_bounds__(256) void gemm_mfma(const unsigned short* __restrict__ A,
                                                 const unsigned short* __restrict__ Bt,
                                                 float* __restrict__ C,
                                                 int K, int ldc) {
    __shared__ unsigned short As[64 * 64];
    __shared__ unsigned short Bs[64 * 64];
    int m0 = blockIdx.y * 64;
    int n0 = blockIdx.x * 64;
    int t = threadIdx.x;
    int lane = t & 63, wave = t >> 6;
    int wr = wave >> 1, wc = wave & 1;
    int srow = t >> 3;        // staging row within 32-row issue
    int sc8  = t & 7;         // dest col-group of 8 bf16
    f32x4 acc[2][2] = {};

    for (int k0 = 0; k0 < K; k0 += 64) {
        __syncthreads();
        #pragma unroll
        for (int i = 0; i < 2; ++i) {
            int row = i * 32 + srow;
            int csrc = sc8 ^ (row & 7);   // inverse-swizzled global source
            __builtin_amdgcn_global_load_lds(
                (const __attribute__((address_space(1))) void*)
                    &A[(size_t)(m0 + row) * K + k0 + csrc * 8],
                (__attribute__((address_space(3))) void*)
                    &As[row * 64 + sc8 * 8], 16, 0, 0);
            __builtin_amdgcn_global_load_lds(
                (const __attribute__((address_space(1))) void*)
                    &Bt[(size_t)(n0 + row) * K + k0 + csrc * 8],
                (__attribute__((address_space(3))) void*)
                    &Bs[row * 64 + sc8 * 8], 16, 0, 0);
        }
        __syncthreads();   // drains vmcnt before barrier -> tile visible
        #pragma unroll
        for (int ks = 0; ks < 2; ++ks) {
            bf16x8 av[2], bv[2];
            #pragma unroll
            for (int f = 0; f < 2; ++f) {
                int ar = wr * 32 + f * 16 + (lane & 15);
                int ac = (ks * 4 + (lane >> 4)) ^ (ar & 7);
                av[f] = *reinterpret_cast<const bf16x8*>(&As[ar * 64 + ac * 8]);
                int br = wc * 32 + f * 16 + (lane & 15);
                int bc = (ks * 4 + (lane >> 4)) ^ (br & 7);
                bv[f] = *reinterpret_cast<const bf16x8*>(&Bs[br * 64 + bc * 8]);
            }
            #pragma unroll
            for (int fm = 0; fm < 2; ++fm)
                #pragma unroll
                for (int fn = 0; fn < 2; ++fn)
                    acc[fm][fn] = __builtin_amdgcn_mfma_f32_16x16x32_bf16(
                        av[fm], bv[fn], acc[fm][fn], 0, 0, 0);
        }
    }
    #pragma unroll
    for (int fm = 0; fm < 2; ++fm)
        #pragma unroll
        for (int fn = 0; fn < 2; ++fn) {
            int row = m0 + wr * 32 + fm * 16 + (lane >> 4) * 4;
            int col = n0 + wc * 32 + fn * 16 + (lane & 15);
            #pragma unroll
            for (int r = 0; r < 4; ++r) {
                float* cp = &C[(size_t)(row + r) * ldc + col];
                if (EPI == 2) *cp += acc[fm][fn][r]; else *cp = acc[fm][fn][r];
            }
        }
}

// -------- causal depthwise conv(4) + bias + SiLU ----------------------------
__global__ void conv_silu_kernel(const float* __restrict__ xr,
                                 const float* __restrict__ cw,
                                 const float* __restrict__ cb,
                                 float* __restrict__ out) {
    int g = blockIdx.x * blockDim.x + threadIdx.x;
    int d = g & (D_INNER - 1);
    int m = g >> 10;
    int l = m & (SEQ_L - 1);
    float4 w = *(const float4*)&cw[d * 4];
    const float* col = &xr[(size_t)m * 2048 + d];
    float x3 = col[0];
    float x2 = (l >= 1) ? col[-2048] : 0.f;
    float x1 = (l >= 2) ? col[-4096] : 0.f;
    float x0 = (l >= 3) ? col[-6144] : 0.f;
    float acc = cb[d] + w.x * x0 + w.y * x1 + w.z * x2 + w.w * x3;
    out[g] = silu_f(acc);
}

// -------- x_proj: C[M,64] = A[M,1024] @ B[1024,64], f32 ---------------------
__global__ __launch_bounds__(256) void xproj_kernel(const float* __restrict__ A,
                                                    const float* __restrict__ Bw,
                                                    float* __restrict__ Cc) {
    __shared__ float Bsh[64][68];
    __shared__ float Ash[4][64];
    int row0 = blockIdx.x * 4;
    int t = threadIdx.x;
    int tr = t >> 6, c = t & 63;
    int kk = t >> 2, cb4 = (t & 3) << 4;
    float acc = 0.f;
    for (int k0 = 0; k0 < 1024; k0 += 64) {
        __syncthreads();
        #pragma unroll
        for (int j = 0; j < 4; ++j) {
            float4 v = *(const float4*)&Bw[(size_t)(k0 + kk) * 64 + cb4 + j * 4];
            *(float4*)&Bsh[kk][cb4 + j * 4] = v;
        }
        Ash[tr][c] = A[(size_t)(row0 + tr) * 1024 + k0 + c];
        __syncthreads();
        #pragma unroll
        for (int k = 0; k < 64; ++k)
            acc = fmaf(Ash[tr][k], Bsh[k][c], acc);
    }
    Cc[(size_t)(row0 + tr) * 64 + c] = acc;
}

// -------- dt_proj f32 GEMM (K=32) with softplus epilogue --------------------
#define BM 64
#define BN 64
#define BKK 16
__global__ __launch_bounds__(256) void gemm_dt(const float* __restrict__ A,
                                               const float* __restrict__ Bm,
                                               const float* __restrict__ bias,
                                               float* __restrict__ C,
                                               int lda, int ldb, int ldc) {
    __shared__ float As[BM][BKK + 4];
    __shared__ float Bs[BKK][BN];
    int tid = threadIdx.x;
    int n0 = blockIdx.x * BN;
    int m0 = blockIdx.y * BM;
    int tx4 = (tid & 15) << 2;
    int ty4 = (tid >> 4) << 2;
    int arow = tid >> 2, akk = (tid & 3) << 2;
    int brow = tid >> 4, bcol = (tid & 15) << 2;
    float acc[4][4] = {};
    for (int k0 = 0; k0 < 32; k0 += BKK) {
        float4 av = *(const float4*)&A[(size_t)(m0 + arow) * lda + k0 + akk];
        float4 bv = *(const float4*)&Bm[(size_t)(k0 + brow) * ldb + n0 + bcol];
        *(float4*)&As[arow][akk] = av;
        *(float4*)&Bs[brow][bcol] = bv;
        __syncthreads();
        #pragma unroll
        for (int k = 0; k < BKK; ++k) {
            float a0 = As[ty4 + 0][k];
            float a1 = As[ty4 + 1][k];
            float a2 = As[ty4 + 2][k];
            float a3 = As[ty4 + 3][k];
            float4 b = *(float4*)&Bs[k][tx4];
            acc[0][0] = fmaf(a0, b.x, acc[0][0]); acc[0][1] = fmaf(a0, b.y, acc[0][1]);
            acc[0][2] = fmaf(a0, b.z, acc[0][2]); acc[0][3] = fmaf(a0, b.w, acc[0][3]);
            acc[1][0] = fmaf(a1, b.x, acc[1][0]); acc[1][1] = fmaf(a1, b.y, acc[1][1]);
            acc[1][2] = fmaf(a1, b.z, acc[1][2]); acc[1][3] = fmaf(a1, b.w, acc[1][3]);
            acc[2][0] = fmaf(a2, b.x, acc[2][0]); acc[2][1] = fmaf(a2, b.y, acc[2][1]);
            acc[2][2] = fmaf(a2, b.z, acc[2][2]); acc[2][3] = fmaf(a2, b.w, acc[2][3]);
            acc[3][0] = fmaf(a3, b.x, acc[3][0]); acc[3][1] = fmaf(a3, b.y, acc[3][1]);
            acc[3][2] = fmaf(a3, b.z, acc[3][2]); acc[3][3] = fmaf(a3, b.w, acc[3][3]);
        }
        __syncthreads();
    }
    #pragma unroll
    for (int i = 0; i < 4; ++i) {
        int m = m0 + ty4 + i;
        float4 bb = *(const float4*)&bias[n0 + tx4];
        float4 v = make_float4(softplus_f(acc[i][0] + bb.x), softplus_f(acc[i][1] + bb.y),
                               softplus_f(acc[i][2] + bb.z), softplus_f(acc[i][3] + bb.w));
        *(float4*)&C[(size_t)m * ldc + n0 + tx4] = v;
    }
}

// ======================= chunk-parallel selective scan =======================
__global__ __launch_bounds__(256) void scan_p1(const float* __restrict__ u_,
                                               const float* __restrict__ delta,
                                               const float* __restrict__ xdbl,
                                               const float* __restrict__ A_log,
                                               float* __restrict__ aprod,
                                               float* __restrict__ hloc) {
    int d = blockIdx.x * 256 + threadIdx.x;
    int b = blockIdx.y;
    int c = blockIdx.z;
    int l0 = c * LC;
    __shared__ float sB[LC][D_STATE];
    for (int i = threadIdx.x; i < LC * D_STATE; i += 256) {
        int l = i >> 4, n = i & 15;
        sB[l][n] = xdbl[((size_t)(b * SEQ_L + l0 + l)) * 64 + DT_RANK + n];
    }
    __syncthreads();
    float A_[D_STATE], h[D_STATE], ap[D_STATE];
    #pragma unroll
    for (int n = 0; n < D_STATE; ++n) {
        A_[n] = -__expf(A_log[(size_t)d * D_STATE + n]);
        h[n] = 0.f; ap[n] = 1.f;
    }
    for (int l = 0; l < LC; ++l) {
        size_t m = (size_t)b * SEQ_L + l0 + l;
        float dt = delta[m * D_INNER + d];
        float uu = u_[m * D_INNER + d];
        float du = dt * uu;
        #pragma unroll
        for (int n = 0; n < D_STATE; ++n) {
            float e = __expf(dt * A_[n]);
            h[n] = fmaf(e, h[n], du * sB[l][n]);
            ap[n] *= e;
        }
    }
    #pragma unroll
    for (int n = 0; n < D_STATE; ++n) {
        size_t o = (((size_t)b * NC + c) * D_STATE + n) * D_INNER + d;
        aprod[o] = ap[n];
        hloc[o] = h[n];
    }
}

__global__ __launch_bounds__(256) void scan_p2(const float* __restrict__ aprod,
                                               float* __restrict__ hloc) {
    int d = blockIdx.x * 256 + threadIdx.x;
    int n = blockIdx.y;
    int b = blockIdx.z;
    float h = 0.f;
    for (int c = 0; c < NC; ++c) {
        size_t o = (((size_t)b * NC + c) * D_STATE + n) * D_INNER + d;
        float ap = aprod[o];
        float lc = hloc[o];
        hloc[o] = h;
        h = fmaf(ap, h, lc);
    }
}

__global__ __launch_bounds__(256) void scan_p3(const float* __restrict__ u_,
                                               const float* __restrict__ delta,
                                               const float* __restrict__ xdbl,
                                               const float* __restrict__ A_log,
                                               const float* __restrict__ Dp,
                                               const float* __restrict__ hinit,
                                               const float* __restrict__ xr,
                                               unsigned short* __restrict__ y) {
    int d = blockIdx.x * 256 + threadIdx.x;
    int b = blockIdx.y;
    int c = blockIdx.z;
    int l0 = c * LC;
    __shared__ float sBC[LC][2 * D_STATE];
    for (int i = threadIdx.x; i < LC * 2 * D_STATE; i += 256) {
        int l = i >> 5, j = i & 31;
        sBC[l][j] = xdbl[((size_t)(b * SEQ_L + l0 + l)) * 64 + DT_RANK + j];
    }
    __syncthreads();
    float A_[D_STATE], h[D_STATE];
    #pragma unroll
    for (int n = 0; n < D_STATE; ++n) {
        A_[n] = -__expf(A_log[(size_t)d * D_STATE + n]);
        size_t o = (((size_t)b * NC + c) * D_STATE + n) * D_INNER + d;
        h[n] = hinit[o];
    }
    float Dd = Dp[d];
    for (int l = 0; l < LC; ++l) {
        size_t m = (size_t)b * SEQ_L + l0 + l;
        float dt = delta[m * D_INNER + d];
        float uu = u_[m * D_INNER + d];
        float du = dt * uu;
        float yv = 0.f;
        #pragma unroll
        for (int n = 0; n < D_STATE; ++n) {
            float e = __expf(dt * A_[n]);
            h[n] = fmaf(e, h[n], du * sBC[l][n]);
            yv = fmaf(h[n], sBC[l][D_STATE + n], yv);
        }
        yv = fmaf(uu, Dd, yv);
        float res = xr[m * 2048 + 1024 + d];
        y[m * D_INNER + d] = f2bf(yv * silu_f(res));
    }
}

// -------- tail: pool, proj, logits ------------------------------------------
__global__ __launch_bounds__(512) void pool_kernel(const float* __restrict__ xf,
                                                   float* __restrict__ pooled) {
    int b = blockIdx.x;
    int d = threadIdx.x;
    float s = 0.f;
    for (int l = 0; l < SEQ_L; ++l)
        s += xf[((size_t)b * SEQ_L + l) * D_MODEL + d];
    pooled[b * D_MODEL + d] = s * (1.f / SEQ_L);
}

__global__ void emb_proj_kernel(const float* __restrict__ pooled,
                                const float* __restrict__ pw,
                                const float* __restrict__ pb,
                                float* __restrict__ out) {
    int b = blockIdx.x;
    int e = threadIdx.x;
    float acc = pb[e];
    for (int k = 0; k < D_MODEL; ++k)
        acc = fmaf(pooled[b * D_MODEL + k], pw[k * 256 + e], acc);
    out[b * 256 + e] = acc;
}

__global__ void logits_kernel(const float* __restrict__ embv,
                              const float* __restrict__ cw,
                              const float* __restrict__ cb,
                              float* __restrict__ out) {
    int t = threadIdx.x;
    if (t < 14) {
        int b = t / 7, c = t % 7;
        float acc = cb[c];
        for (int k = 0; k < 256; ++k)
            acc = fmaf(embv[b * 256 + k], cw[k * 7 + c], acc);
        out[b * 7 + c] = acc;
    }
}

extern "C" void kernel_launch(void* const* d_in, const int* in_sizes, int n_in,
                              void* d_out, int out_size, void* d_ws, size_t ws_size,
                              hipStream_t stream) {
    const int*   ids    = (const int*)d_in[0];
    const float* emb    = (const float*)d_in[1];
    const float* norm_w = (const float*)d_in[2];
    const float* in_w   = (const float*)d_in[3];
    const float* conv_w = (const float*)d_in[4];
    const float* conv_b = (const float*)d_in[5];
    const float* xp_w   = (const float*)d_in[6];
    const float* dt_w   = (const float*)d_in[7];
    const float* dt_b   = (const float*)d_in[8];
    const float* A_log  = (const float*)d_in[9];
    const float* Dp     = (const float*)d_in[10];
    const float* out_w  = (const float*)d_in[11];
    const float* normf  = (const float*)d_in[12];
    const float* proj_w = (const float*)d_in[13];
    const float* proj_b = (const float*)d_in[14];
    const float* cls_w  = (const float*)d_in[15];
    const float* cls_b  = (const float*)d_in[16];
    float* out = (float*)d_out;

    float* ws     = (float*)d_ws;
    float* x      = ws;                      // 1,048,576
    float* xn     = x + 1048576;             // 1,048,576 (hloc alias)
    float* xr     = xn + 1048576;            // 4,194,304
    float* xconv  = xr + 4194304;            // 2,097,152 (out_wt alias)
    float* xdbl   = xconv + 2097152;         //   131,072
    float* delta  = xdbl + 131072;           // 2,097,152 (in_wt + xn_bf alias)
    float* yb     = delta + 2097152;         // 2,097,152 (aprod + yb_bf)
    float* pooled = yb + 2097152;            //     1,024

    float* aprod  = yb;
    float* hloc   = xn;
    unsigned short* in_wt  = (unsigned short*)delta;              // 1M bf16
    unsigned short* xn_bf  = (unsigned short*)(delta + 524288);   // 1M bf16
    unsigned short* out_wt = (unsigned short*)xconv;              // 512K bf16
    unsigned short* yb_bf  = (unsigned short*)(yb + 1048576);     // 2M bf16

    embed_kernel<<<1024, 256, 0, stream>>>(ids, emb, x);

    for (int i = 0; i < NLAYER; ++i) {
        // weight cast+transpose: in_w [512][2048] -> in_wt [2048][512]
        castT_kernel<<<dim3(64, 16), 256, 0, stream>>>(
            in_w + (size_t)i * D_MODEL * 2 * D_INNER, in_wt, 512, 2048);
        rmsnorm_bf_kernel<<<M_ROWS, 64, 0, stream>>>(x, norm_w + i * D_MODEL, xn_bf);
        gemm_mfma<0><<<dim3(2048 / 64, M_ROWS / 64), 256, 0, stream>>>(
            xn_bf, in_wt, xr, 512, 2048);
        conv_silu_kernel<<<(M_ROWS * D_INNER) / 256, 256, 0, stream>>>(
            xr, conv_w + i * D_INNER * 4, conv_b + i * D_INNER, xconv);
        xproj_kernel<<<M_ROWS / 4, 256, 0, stream>>>(
            xconv, xp_w + (size_t)i * D_INNER * 64, xdbl);
        gemm_dt<<<dim3(1024 / BN, M_ROWS / BM), 256, 0, stream>>>(
            xdbl, dt_w + (size_t)i * DT_RANK * D_INNER, dt_b + i * D_INNER, delta,
            64, 1024, 1024);

        scan_p1<<<dim3(D_INNER / 256, BATCH, NC), 256, 0, stream>>>(
            xconv, delta, xdbl, A_log + (size_t)i * D_INNER * D_STATE, aprod, hloc);
        scan_p2<<<dim3(D_INNER / 256, D_STATE, BATCH), 256, 0, stream>>>(
            aprod, hloc);
        scan_p3<<<dim3(D_INNER / 256, BATCH, NC), 256, 0, stream>>>(
            xconv, delta, xdbl, A_log + (size_t)i * D_INNER * D_STATE,
            Dp + (size_t)i * D_INNER, hloc, xr, yb_bf);

        // weight cast+transpose: out_w [1024][512] -> out_wt [512][1024]
        castT_kernel<<<dim3(16, 32), 256, 0, stream>>>(
            out_w + (size_t)i * D_INNER * D_MODEL, out_wt, 1024, 512);
        gemm_mfma<2><<<dim3(512 / 64, M_ROWS / 64), 256, 0, stream>>>(
            yb_bf, out_wt, x, 1024, 512);
    }

    rmsnorm_kernel<<<M_ROWS, 64, 0, stream>>>(x, normf, xn);
    pool_kernel<<<BATCH, 512, 0, stream>>>(xn, pooled);
    emb_proj_kernel<<<BATCH, 256, 0, stream>>>(pooled, proj_w, proj_b, out + 14);
    logits_kernel<<<1, 64, 0, stream>>>(out + 14, cls_w, cls_b, out);
}

// Round 4
// 260.925 us; speedup vs baseline: 7.7952x; 1.2368x over previous
//
#include <hip/hip_runtime.h>
#include <cstddef>

#define D_MODEL   512
#define D_INNER   1024
#define D_STATE   16
#define DT_RANK   32
#define SEQ_L     1024
#define BATCH     2
#define NLAYER    2
#define M_ROWS    (BATCH * SEQ_L)   // 2048
#define NC        32                // scan chunks
#define LC        (SEQ_L / NC)      // 32 timesteps per chunk

typedef __bf16 bf16x8 __attribute__((ext_vector_type(8)));
typedef float  f32x4  __attribute__((ext_vector_type(4)));

__device__ __forceinline__ float softplus_f(float x) {
    return fmaxf(x, 0.f) + log1pf(expf(-fabsf(x)));
}
__device__ __forceinline__ float silu_f(float x) {
    return x / (1.f + __expf(-x));
}
__device__ __forceinline__ unsigned short f2bf(float f) {
    unsigned u = __float_as_uint(f);
    return (unsigned short)((u + 0x7fffu + ((u >> 16) & 1u)) >> 16);
}
__device__ __forceinline__ unsigned pack_bf2(float lo, float hi) {
    return (unsigned)f2bf(lo) | ((unsigned)f2bf(hi) << 16);
}

// -------- embedding gather --------------------------------------------------
__global__ void embed_kernel(const int* __restrict__ ids,
                             const float* __restrict__ emb,
                             float* __restrict__ x) {
    int g = blockIdx.x * blockDim.x + threadIdx.x;
    int c = (g & 127) << 2;
    int m = g >> 7;
    int row = ids[m];
    *(float4*)&x[(size_t)m * D_MODEL + c] =
        *(const float4*)&emb[(size_t)row * D_MODEL + c];
}

// -------- rmsnorm (bf16 out, feeds MFMA in_proj) ----------------------------
__global__ __launch_bounds__(64) void rmsnorm_bf_kernel(const float* __restrict__ x,
                                                        const float* __restrict__ w,
                                                        unsigned short* __restrict__ out) {
    int row = blockIdx.x;
    int tid = threadIdx.x;
    const float* xp = x + (size_t)row * D_MODEL;
    float4 v0 = *(const float4*)&xp[tid * 4];
    float4 v1 = *(const float4*)&xp[256 + tid * 4];
    float ss = v0.x*v0.x + v0.y*v0.y + v0.z*v0.z + v0.w*v0.w
             + v1.x*v1.x + v1.y*v1.y + v1.z*v1.z + v1.w*v1.w;
    #pragma unroll
    for (int off = 32; off > 0; off >>= 1) ss += __shfl_xor(ss, off);
    float scale = rsqrtf(ss * (1.f / D_MODEL) + 1e-5f);
    float4 w0 = *(const float4*)&w[tid * 4];
    float4 w1 = *(const float4*)&w[256 + tid * 4];
    unsigned short* op = out + (size_t)row * D_MODEL;
    uint2 p0, p1;
    p0.x = pack_bf2(v0.x * scale * w0.x, v0.y * scale * w0.y);
    p0.y = pack_bf2(v0.z * scale * w0.z, v0.w * scale * w0.w);
    p1.x = pack_bf2(v1.x * scale * w1.x, v1.y * scale * w1.y);
    p1.y = pack_bf2(v1.z * scale * w1.z, v1.w * scale * w1.w);
    *(uint2*)&op[tid * 4] = p0;
    *(uint2*)&op[256 + tid * 4] = p1;
}

// -------- cast + transpose weight: W f32 [K][N] -> Wt bf16 [N][K] -----------
__global__ __launch_bounds__(256) void castT_kernel(const float* __restrict__ W,
                                                    unsigned short* __restrict__ Wt,
                                                    int K, int N) {
    __shared__ float tile[32][33];
    int n0 = blockIdx.x * 32, k0 = blockIdx.y * 32;
    int tx = threadIdx.x & 31, ty = threadIdx.x >> 5;   // ty 0..7
    #pragma unroll
    for (int i = 0; i < 4; ++i)
        tile[ty + i*8][tx] = W[(size_t)(k0 + ty + i*8) * N + n0 + tx];
    __syncthreads();
    #pragma unroll
    for (int i = 0; i < 4; ++i)
        Wt[(size_t)(n0 + ty + i*8) * K + k0 + tx] = f2bf(tile[tx][ty + i*8]);
}

// -------- bf16 MFMA GEMM: C[M,N](f32) = A[M,K](bf16) @ Bt[N,K](bf16)^T ------
template<int EPI>
__global__ __launch_bounds__(256) void gemm_mfma(const unsigned short* __restrict__ A,
                                                 const unsigned short* __restrict__ Bt,
                                                 float* __restrict__ C,
                                                 int K, int ldc) {
    __shared__ unsigned short As[64 * 64];
    __shared__ unsigned short Bs[64 * 64];
    int m0 = blockIdx.y * 64;
    int n0 = blockIdx.x * 64;
    int t = threadIdx.x;
    int lane = t & 63, wave = t >> 6;
    int wr = wave >> 1, wc = wave & 1;
    int srow = t >> 3;
    int sc8  = t & 7;
    f32x4 acc[2][2] = {};

    for (int k0 = 0; k0 < K; k0 += 64) {
        __syncthreads();
        #pragma unroll
        for (int i = 0; i < 2; ++i) {
            int row = i * 32 + srow;
            int csrc = sc8 ^ (row & 7);
            __builtin_amdgcn_global_load_lds(
                (const __attribute__((address_space(1))) void*)
                    &A[(size_t)(m0 + row) * K + k0 + csrc * 8],
                (__attribute__((address_space(3))) void*)
                    &As[row * 64 + sc8 * 8], 16, 0, 0);
            __builtin_amdgcn_global_load_lds(
                (const __attribute__((address_space(1))) void*)
                    &Bt[(size_t)(n0 + row) * K + k0 + csrc * 8],
                (__attribute__((address_space(3))) void*)
                    &Bs[row * 64 + sc8 * 8], 16, 0, 0);
        }
        __syncthreads();
        #pragma unroll
        for (int ks = 0; ks < 2; ++ks) {
            bf16x8 av[2], bv[2];
            #pragma unroll
            for (int f = 0; f < 2; ++f) {
                int ar = wr * 32 + f * 16 + (lane & 15);
                int ac = (ks * 4 + (lane >> 4)) ^ (ar & 7);
                av[f] = *reinterpret_cast<const bf16x8*>(&As[ar * 64 + ac * 8]);
                int br = wc * 32 + f * 16 + (lane & 15);
                int bc = (ks * 4 + (lane >> 4)) ^ (br & 7);
                bv[f] = *reinterpret_cast<const bf16x8*>(&Bs[br * 64 + bc * 8]);
            }
            #pragma unroll
            for (int fm = 0; fm < 2; ++fm)
                #pragma unroll
                for (int fn = 0; fn < 2; ++fn)
                    acc[fm][fn] = __builtin_amdgcn_mfma_f32_16x16x32_bf16(
                        av[fm], bv[fn], acc[fm][fn], 0, 0, 0);
        }
    }
    #pragma unroll
    for (int fm = 0; fm < 2; ++fm)
        #pragma unroll
        for (int fn = 0; fn < 2; ++fn) {
            int row = m0 + wr * 32 + fm * 16 + (lane >> 4) * 4;
            int col = n0 + wc * 32 + fn * 16 + (lane & 15);
            #pragma unroll
            for (int r = 0; r < 4; ++r) {
                float* cp = &C[(size_t)(row + r) * ldc + col];
                if (EPI == 2) *cp += acc[fm][fn][r]; else *cp = acc[fm][fn][r];
            }
        }
}

// -------- causal depthwise conv(4) + bias + SiLU ----------------------------
__global__ void conv_silu_kernel(const float* __restrict__ xr,
                                 const float* __restrict__ cw,
                                 const float* __restrict__ cb,
                                 float* __restrict__ out) {
    int g = blockIdx.x * blockDim.x + threadIdx.x;
    int d = g & (D_INNER - 1);
    int m = g >> 10;
    int l = m & (SEQ_L - 1);
    float4 w = *(const float4*)&cw[d * 4];
    const float* col = &xr[(size_t)m * 2048 + d];
    float x3 = col[0];
    float x2 = (l >= 1) ? col[-2048] : 0.f;
    float x1 = (l >= 2) ? col[-4096] : 0.f;
    float x0 = (l >= 3) ? col[-6144] : 0.f;
    float acc = cb[d] + w.x * x0 + w.y * x1 + w.z * x2 + w.w * x3;
    out[g] = silu_f(acc);
}

// -------- x_proj: C[M,64] = A[M,1024] @ B[1024,64], f32 ---------------------
__global__ __launch_bounds__(256) void xproj_kernel(const float* __restrict__ A,
                                                    const float* __restrict__ Bw,
                                                    float* __restrict__ Cc) {
    __shared__ float Bsh[64][68];
    __shared__ float Ash[4][64];
    int row0 = blockIdx.x * 4;
    int t = threadIdx.x;
    int tr = t >> 6, c = t & 63;
    int kk = t >> 2, cb4 = (t & 3) << 4;
    float acc = 0.f;
    for (int k0 = 0; k0 < 1024; k0 += 64) {
        __syncthreads();
        #pragma unroll
        for (int j = 0; j < 4; ++j) {
            float4 v = *(const float4*)&Bw[(size_t)(k0 + kk) * 64 + cb4 + j * 4];
            *(float4*)&Bsh[kk][cb4 + j * 4] = v;
        }
        Ash[tr][c] = A[(size_t)(row0 + tr) * 1024 + k0 + c];
        __syncthreads();
        #pragma unroll
        for (int k = 0; k < 64; ++k)
            acc = fmaf(Ash[tr][k], Bsh[k][c], acc);
    }
    Cc[(size_t)(row0 + tr) * 64 + c] = acc;
}

// -------- dt_proj f32 GEMM (K=32) with softplus epilogue --------------------
#define BM 64
#define BN 64
#define BKK 16
__global__ __launch_bounds__(256) void gemm_dt(const float* __restrict__ A,
                                               const float* __restrict__ Bm,
                                               const float* __restrict__ bias,
                                               float* __restrict__ C,
                                               int lda, int ldb, int ldc) {
    __shared__ float As[BM][BKK + 4];
    __shared__ float Bs[BKK][BN];
    int tid = threadIdx.x;
    int n0 = blockIdx.x * BN;
    int m0 = blockIdx.y * BM;
    int tx4 = (tid & 15) << 2;
    int ty4 = (tid >> 4) << 2;
    int arow = tid >> 2, akk = (tid & 3) << 2;
    int brow = tid >> 4, bcol = (tid & 15) << 2;
    float acc[4][4] = {};
    for (int k0 = 0; k0 < 32; k0 += BKK) {
        float4 av = *(const float4*)&A[(size_t)(m0 + arow) * lda + k0 + akk];
        float4 bv = *(const float4*)&Bm[(size_t)(k0 + brow) * ldb + n0 + bcol];
        *(float4*)&As[arow][akk] = av;
        *(float4*)&Bs[brow][bcol] = bv;
        __syncthreads();
        #pragma unroll
        for (int k = 0; k < BKK; ++k) {
            float a0 = As[ty4 + 0][k];
            float a1 = As[ty4 + 1][k];
            float a2 = As[ty4 + 2][k];
            float a3 = As[ty4 + 3][k];
            float4 b = *(float4*)&Bs[k][tx4];
            acc[0][0] = fmaf(a0, b.x, acc[0][0]); acc[0][1] = fmaf(a0, b.y, acc[0][1]);
            acc[0][2] = fmaf(a0, b.z, acc[0][2]); acc[0][3] = fmaf(a0, b.w, acc[0][3]);
            acc[1][0] = fmaf(a1, b.x, acc[1][0]); acc[1][1] = fmaf(a1, b.y, acc[1][1]);
            acc[1][2] = fmaf(a1, b.z, acc[1][2]); acc[1][3] = fmaf(a1, b.w, acc[1][3]);
            acc[2][0] = fmaf(a2, b.x, acc[2][0]); acc[2][1] = fmaf(a2, b.y, acc[2][1]);
            acc[2][2] = fmaf(a2, b.z, acc[2][2]); acc[2][3] = fmaf(a2, b.w, acc[2][3]);
            acc[3][0] = fmaf(a3, b.x, acc[3][0]); acc[3][1] = fmaf(a3, b.y, acc[3][1]);
            acc[3][2] = fmaf(a3, b.z, acc[3][2]); acc[3][3] = fmaf(a3, b.w, acc[3][3]);
        }
        __syncthreads();
    }
    #pragma unroll
    for (int i = 0; i < 4; ++i) {
        int m = m0 + ty4 + i;
        float4 bb = *(const float4*)&bias[n0 + tx4];
        float4 v = make_float4(softplus_f(acc[i][0] + bb.x), softplus_f(acc[i][1] + bb.y),
                               softplus_f(acc[i][2] + bb.z), softplus_f(acc[i][3] + bb.w));
        *(float4*)&C[(size_t)m * ldc + n0 + tx4] = v;
    }
}

// ======================= chunk-parallel selective scan =======================
__global__ __launch_bounds__(256) void scan_p1(const float* __restrict__ u_,
                                               const float* __restrict__ delta,
                                               const float* __restrict__ xdbl,
                                               const float* __restrict__ A_log,
                                               float* __restrict__ aprod,
                                               float* __restrict__ hloc) {
    int d = blockIdx.x * 256 + threadIdx.x;
    int b = blockIdx.y;
    int c = blockIdx.z;
    int l0 = c * LC;
    __shared__ float sB[LC][D_STATE];
    for (int i = threadIdx.x; i < LC * D_STATE; i += 256) {
        int l = i >> 4, n = i & 15;
        sB[l][n] = xdbl[((size_t)(b * SEQ_L + l0 + l)) * 64 + DT_RANK + n];
    }
    __syncthreads();
    float A_[D_STATE], h[D_STATE], ap[D_STATE];
    #pragma unroll
    for (int n = 0; n < D_STATE; ++n) {
        A_[n] = -__expf(A_log[(size_t)d * D_STATE + n]);
        h[n] = 0.f; ap[n] = 1.f;
    }
    for (int l = 0; l < LC; ++l) {
        size_t m = (size_t)b * SEQ_L + l0 + l;
        float dt = delta[m * D_INNER + d];
        float uu = u_[m * D_INNER + d];
        float du = dt * uu;
        #pragma unroll
        for (int n = 0; n < D_STATE; ++n) {
            float e = __expf(dt * A_[n]);
            h[n] = fmaf(e, h[n], du * sB[l][n]);
            ap[n] *= e;
        }
    }
    #pragma unroll
    for (int n = 0; n < D_STATE; ++n) {
        size_t o = (((size_t)b * NC + c) * D_STATE + n) * D_INNER + d;
        aprod[o] = ap[n];
        hloc[o] = h[n];
    }
}

__global__ __launch_bounds__(256) void scan_p2(const float* __restrict__ aprod,
                                               float* __restrict__ hloc) {
    int d = blockIdx.x * 256 + threadIdx.x;
    int n = blockIdx.y;
    int b = blockIdx.z;
    float h = 0.f;
    for (int c = 0; c < NC; ++c) {
        size_t o = (((size_t)b * NC + c) * D_STATE + n) * D_INNER + d;
        float ap = aprod[o];
        float lc = hloc[o];
        hloc[o] = h;
        h = fmaf(ap, h, lc);
    }
}

__global__ __launch_bounds__(256) void scan_p3(const float* __restrict__ u_,
                                               const float* __restrict__ delta,
                                               const float* __restrict__ xdbl,
                                               const float* __restrict__ A_log,
                                               const float* __restrict__ Dp,
                                               const float* __restrict__ hinit,
                                               const float* __restrict__ xr,
                                               unsigned short* __restrict__ y) {
    int d = blockIdx.x * 256 + threadIdx.x;
    int b = blockIdx.y;
    int c = blockIdx.z;
    int l0 = c * LC;
    __shared__ float sBC[LC][2 * D_STATE];
    for (int i = threadIdx.x; i < LC * 2 * D_STATE; i += 256) {
        int l = i >> 5, j = i & 31;
        sBC[l][j] = xdbl[((size_t)(b * SEQ_L + l0 + l)) * 64 + DT_RANK + j];
    }
    __syncthreads();
    float A_[D_STATE], h[D_STATE];
    #pragma unroll
    for (int n = 0; n < D_STATE; ++n) {
        A_[n] = -__expf(A_log[(size_t)d * D_STATE + n]);
        size_t o = (((size_t)b * NC + c) * D_STATE + n) * D_INNER + d;
        h[n] = hinit[o];
    }
    float Dd = Dp[d];
    for (int l = 0; l < LC; ++l) {
        size_t m = (size_t)b * SEQ_L + l0 + l;
        float dt = delta[m * D_INNER + d];
        float uu = u_[m * D_INNER + d];
        float du = dt * uu;
        float yv = 0.f;
        #pragma unroll
        for (int n = 0; n < D_STATE; ++n) {
            float e = __expf(dt * A_[n]);
            h[n] = fmaf(e, h[n], du * sBC[l][n]);
            yv = fmaf(h[n], sBC[l][D_STATE + n], yv);
        }
        yv = fmaf(uu, Dd, yv);
        float res = xr[m * 2048 + 1024 + d];
        y[m * D_INNER + d] = f2bf(yv * silu_f(res));
    }
}

// ============== fused final rmsnorm + mean-pool (chunked over L) ============
// grid (B*32); 4 waves/block, each wave rmsnorms 8 rows and accumulates
// v*scale in registers (w factored out); LDS reduce -> partial[b][c][512]
__global__ __launch_bounds__(256) void rms_pool1(const float* __restrict__ x,
                                                 float* __restrict__ partial) {
    int blk = blockIdx.x;
    int b = blk >> 5, c = blk & 31;
    int wave = threadIdx.x >> 6, lane = threadIdx.x & 63;
    int row0 = b * SEQ_L + c * 32 + wave * 8;
    float4 a0 = make_float4(0.f, 0.f, 0.f, 0.f);
    float4 a1 = make_float4(0.f, 0.f, 0.f, 0.f);
    for (int r = 0; r < 8; ++r) {
        const float* xp = x + (size_t)(row0 + r) * D_MODEL;
        float4 v0 = *(const float4*)&xp[lane * 4];
        float4 v1 = *(const float4*)&xp[256 + lane * 4];
        float ss = v0.x*v0.x + v0.y*v0.y + v0.z*v0.z + v0.w*v0.w
                 + v1.x*v1.x + v1.y*v1.y + v1.z*v1.z + v1.w*v1.w;
        #pragma unroll
        for (int off = 32; off > 0; off >>= 1) ss += __shfl_xor(ss, off);
        float s = rsqrtf(ss * (1.f / D_MODEL) + 1e-5f);
        a0.x = fmaf(v0.x, s, a0.x); a0.y = fmaf(v0.y, s, a0.y);
        a0.z = fmaf(v0.z, s, a0.z); a0.w = fmaf(v0.w, s, a0.w);
        a1.x = fmaf(v1.x, s, a1.x); a1.y = fmaf(v1.y, s, a1.y);
        a1.z = fmaf(v1.z, s, a1.z); a1.w = fmaf(v1.w, s, a1.w);
    }
    __shared__ float red[4][512];
    *(float4*)&red[wave][lane * 4] = a0;
    *(float4*)&red[wave][256 + lane * 4] = a1;
    __syncthreads();
    int d = threadIdx.x * 2;
    float s0 = red[0][d] + red[1][d] + red[2][d] + red[3][d];
    float s1 = red[0][d+1] + red[1][d+1] + red[2][d+1] + red[3][d+1];
    partial[(size_t)blk * 512 + d]     = s0;
    partial[(size_t)blk * 512 + d + 1] = s1;
}

__global__ __launch_bounds__(512) void pool2_kernel(const float* __restrict__ partial,
                                                    const float* __restrict__ w,
                                                    float* __restrict__ pooled) {
    int b = blockIdx.x, d = threadIdx.x;
    float s = 0.f;
    #pragma unroll
    for (int c = 0; c < 32; ++c)
        s += partial[((size_t)b * 32 + c) * 512 + d];
    pooled[b * 512 + d] = s * (1.f / SEQ_L) * w[d];
}

// ---- emb_proj: k-split partials, then reduce+bias --------------------------
__global__ __launch_bounds__(256) void embp1_kernel(const float* __restrict__ pooled,
                                                    const float* __restrict__ pw,
                                                    float* __restrict__ partial) {
    int b = blockIdx.x, kc = blockIdx.y;
    int e = threadIdx.x;
    float acc = 0.f;
    #pragma unroll 8
    for (int i = 0; i < 64; ++i) {
        int k = kc * 64 + i;
        acc = fmaf(pooled[b * 512 + k], pw[(size_t)k * 256 + e], acc);
    }
    partial[((size_t)b * 8 + kc) * 256 + e] = acc;
}

__global__ __launch_bounds__(512) void embp2_kernel(const float* __restrict__ partial,
                                                    const float* __restrict__ pb,
                                                    float* __restrict__ out14) {
    int t = threadIdx.x;
    int b = t >> 8, e = t & 255;
    float s = pb[e];
    #pragma unroll
    for (int kc = 0; kc < 8; ++kc)
        s += partial[((size_t)b * 8 + kc) * 256 + e];
    out14[b * 256 + e] = s;
}

// ---- logits: one wave per (b,c) output -------------------------------------
__global__ __launch_bounds__(896) void logits_kernel(const float* __restrict__ embv,
                                                     const float* __restrict__ cw,
                                                     const float* __restrict__ cb,
                                                     float* __restrict__ out) {
    int wave = threadIdx.x >> 6, lane = threadIdx.x & 63;
    int b = wave / 7, c = wave % 7;
    float acc = 0.f;
    #pragma unroll
    for (int i = 0; i < 4; ++i) {
        int k = lane + i * 64;
        acc = fmaf(embv[b * 256 + k], cw[k * 7 + c], acc);
    }
    #pragma unroll
    for (int off = 32; off > 0; off >>= 1) acc += __shfl_xor(acc, off);
    if (lane == 0) out[b * 7 + c] = acc + cb[c];
}

extern "C" void kernel_launch(void* const* d_in, const int* in_sizes, int n_in,
                              void* d_out, int out_size, void* d_ws, size_t ws_size,
                              hipStream_t stream) {
    const int*   ids    = (const int*)d_in[0];
    const float* emb    = (const float*)d_in[1];
    const float* norm_w = (const float*)d_in[2];
    const float* in_w   = (const float*)d_in[3];
    const float* conv_w = (const float*)d_in[4];
    const float* conv_b = (const float*)d_in[5];
    const float* xp_w   = (const float*)d_in[6];
    const float* dt_w   = (const float*)d_in[7];
    const float* dt_b   = (const float*)d_in[8];
    const float* A_log  = (const float*)d_in[9];
    const float* Dp     = (const float*)d_in[10];
    const float* out_w  = (const float*)d_in[11];
    const float* normf  = (const float*)d_in[12];
    const float* proj_w = (const float*)d_in[13];
    const float* proj_b = (const float*)d_in[14];
    const float* cls_w  = (const float*)d_in[15];
    const float* cls_b  = (const float*)d_in[16];
    float* out = (float*)d_out;

    float* ws     = (float*)d_ws;
    float* x      = ws;                      // 1,048,576
    float* xn     = x + 1048576;             // 1,048,576 (hloc / pool partial)
    float* xr     = xn + 1048576;            // 4,194,304
    float* xconv  = xr + 4194304;            // 2,097,152 (out_wt alias)
    float* xdbl   = xconv + 2097152;         //   131,072
    float* delta  = xdbl + 131072;           // 2,097,152 (in_wt + xn_bf alias)
    float* yb     = delta + 2097152;         // 2,097,152 (aprod + yb_bf)
    float* pooled = yb + 2097152;            //     1,024
    float* eparts = pooled + 1024;           //     4,096

    float* aprod  = yb;
    float* hloc   = xn;
    float* ppart  = xn;
    unsigned short* in_wt  = (unsigned short*)delta;
    unsigned short* xn_bf  = (unsigned short*)(delta + 524288);
    unsigned short* out_wt = (unsigned short*)xconv;
    unsigned short* yb_bf  = (unsigned short*)(yb + 1048576);

    embed_kernel<<<1024, 256, 0, stream>>>(ids, emb, x);

    for (int i = 0; i < NLAYER; ++i) {
        castT_kernel<<<dim3(64, 16), 256, 0, stream>>>(
            in_w + (size_t)i * D_MODEL * 2 * D_INNER, in_wt, 512, 2048);
        rmsnorm_bf_kernel<<<M_ROWS, 64, 0, stream>>>(x, norm_w + i * D_MODEL, xn_bf);
        gemm_mfma<0><<<dim3(2048 / 64, M_ROWS / 64), 256, 0, stream>>>(
            xn_bf, in_wt, xr, 512, 2048);
        conv_silu_kernel<<<(M_ROWS * D_INNER) / 256, 256, 0, stream>>>(
            xr, conv_w + i * D_INNER * 4, conv_b + i * D_INNER, xconv);
        xproj_kernel<<<M_ROWS / 4, 256, 0, stream>>>(
            xconv, xp_w + (size_t)i * D_INNER * 64, xdbl);
        gemm_dt<<<dim3(1024 / BN, M_ROWS / BM), 256, 0, stream>>>(
            xdbl, dt_w + (size_t)i * DT_RANK * D_INNER, dt_b + i * D_INNER, delta,
            64, 1024, 1024);

        scan_p1<<<dim3(D_INNER / 256, BATCH, NC), 256, 0, stream>>>(
            xconv, delta, xdbl, A_log + (size_t)i * D_INNER * D_STATE, aprod, hloc);
        scan_p2<<<dim3(D_INNER / 256, D_STATE, BATCH), 256, 0, stream>>>(
            aprod, hloc);
        scan_p3<<<dim3(D_INNER / 256, BATCH, NC), 256, 0, stream>>>(
            xconv, delta, xdbl, A_log + (size_t)i * D_INNER * D_STATE,
            Dp + (size_t)i * D_INNER, hloc, xr, yb_bf);

        castT_kernel<<<dim3(16, 32), 256, 0, stream>>>(
            out_w + (size_t)i * D_INNER * D_MODEL, out_wt, 1024, 512);
        gemm_mfma<2><<<dim3(512 / 64, M_ROWS / 64), 256, 0, stream>>>(
            yb_bf, out_wt, x, 1024, 512);
    }

    rms_pool1<<<BATCH * 32, 256, 0, stream>>>(x, ppart);
    pool2_kernel<<<BATCH, 512, 0, stream>>>(ppart, normf, pooled);
    embp1_kernel<<<dim3(BATCH, 8), 256, 0, stream>>>(pooled, proj_w, eparts);
    embp2_kernel<<<1, 512, 0, stream>>>(eparts, proj_b, out + 14);
    logits_kernel<<<1, 896, 0, stream>>>(out + 14, cls_w, cls_b, out);
}